// Round 19
// baseline (181.353 us; speedup 1.0000x reference)
//
#include <hip/hip_runtime.h>
#include <stdint.h>

#define HH    256
#define DD    96
#define NH    6
#define WSZ   8

typedef __bf16 bf16_t;
typedef bf16_t bf16x8 __attribute__((ext_vector_type(8)));
typedef short  s16x4  __attribute__((ext_vector_type(4)));
typedef float  f32x4  __attribute__((ext_vector_type(4)));

union U2  { bf16_t h[2]; uint32_t u; };
union Upk { uint32_t u[2]; s16x4 s; };

#define LOG2E 1.44269504088896f

static __device__ __forceinline__ uint32_t pack2(float a, float b) {
    U2 x; x.h[0] = (bf16_t)a; x.h[1] = (bf16_t)b; return x.u;
}

static __device__ __forceinline__ f32x4 mfma16(s16x4 a, s16x4 b, f32x4 c) {
#if __has_builtin(__builtin_amdgcn_mfma_f32_16x16x16bf16_1k)
    return __builtin_amdgcn_mfma_f32_16x16x16bf16_1k(a, b, c, 0, 0, 0);
#else
    f32x4 d;
    asm volatile("v_mfma_f32_16x16x16_bf16 %0, %1, %2, %3"
                 : "=v"(d) : "v"(a), "v"(b), "v"(c));
    return d;
#endif
}

static __device__ __forceinline__ float fast_exp2(float x) {
#if __has_builtin(__builtin_amdgcn_exp2f)
    return __builtin_amdgcn_exp2f(x);
#else
    return exp2f(x);
#endif
}

static __device__ __forceinline__ float fast_rcp(float x) {
#if __has_builtin(__builtin_amdgcn_rcpf)
    return __builtin_amdgcn_rcpf(x);
#else
    return 1.0f / x;
#endif
}

// ---- workspace layout (bytes) ----
#define OFF_WQT  0        // Q,K transposed A-frags (bf16): 36 frags * 512 el = 36864 B
#define OFF_WV   36864    // V B-frags: 18 frags * 512 el = 18432 B
#define OFF_WO   55296    // out-proj frags: 18 frags = 18432 B
#define OFF_RPE  73728    // rpe * log2e in C-frag layout [h][nt][kt][lane][4] f32 = 98304 B
// total 172032 B

// swizzled element index into a [64][128] bf16 buffer (16B-chunk XOR)
static __device__ __forceinline__ int swz(int row, int col) {
    return row * 128 + ((((col >> 3) ^ (row & 15)) & 15) << 3) + (col & 7);
}

__global__ __launch_bounds__(256)
void prep_kernel(const float* __restrict__ wqkv, const float* __restrict__ wout,
                 const float* __restrict__ rpe, char* __restrict__ ws)
{
    bf16_t* wqt = (bf16_t*)(ws + OFF_WQT);
    bf16_t* wv  = (bf16_t*)(ws + OFF_WV);
    bf16_t* wo  = (bf16_t*)(ws + OFF_WO);
    float*  rpe_b = (float*)(ws + OFF_RPE);

    int idx = blockIdx.x * 256 + threadIdx.x;
    {
        int j = idx & 7, lane = (idx >> 3) & 63, frag = idx >> 9;
        int c = lane & 15, g = lane >> 4;
        // Q,K transposed A-frags: lane(c,g) holds W^T[head-dim c][k=ks*32+g*8+j]
        if (idx < 18432) {
            int ks = frag % 3, r2 = frag / 3, wh = r2 % 6, t = r2 / 6;  // t: 0=Q,1=K
            int k = ks * 32 + g * 8 + j;
            wqt[idx] = (bf16_t)wqkv[k * 288 + t * 96 + wh * 16 + c];
        }
        // V B-frags + out-proj frags: lane(c,g) holds W[k=ks*32+g*8+j][n=wh*16+c]
        if (idx < 9216) {
            int ks = frag % 3, wh = frag / 3;
            int k = ks * 32 + g * 8 + j;
            wv[idx] = (bf16_t)wqkv[k * 288 + 192 + wh * 16 + c];
            wo[idx] = (bf16_t)wout[k * 96 + wh * 16 + c];
        }
    }
    // rpe * log2e in QK^T C-fragment layout: [h][nt][kt][lane][i]
    if (idx < 24576) {
        int i = idx & 3, lane = (idx >> 2) & 63, kt = (idx >> 8) & 3,
            nt = (idx >> 10) & 3, h = idx >> 12;
        int c = lane & 15, g = lane >> 4;
        int k = kt * 16 + g * 4 + i, q = nt * 16 + c;
        int qr = q >> 3, qc = q & 7, kr = k >> 3, kc = k & 7;
        rpe_b[idx] = rpe[((qr - kr + 7) * 15 + (qc - kc + 7)) * NH + h] * LOG2E;
    }
}

// one nt-tile of the attention phase; EDGE_ON is a compile-time 0/1
#define ATTN_LOOP(EDGE_ON)                                                      \
    _Pragma("unroll")                                                           \
    for (int nt = 0; nt < 4; ++nt) {                                            \
        f32x4 stc[4];                                                           \
        _Pragma("unroll")                                                       \
        for (int kt = 0; kt < 4; ++kt) {                                        \
            const f32x4 rc = *(const f32x4*)&rpe_b[(((w * 4 + nt) * 4 + kt) << 8) + lane * 4]; \
            stc[kt] = mfma16(akb[kt], aqb[nt], rc);                             \
        }                                                                       \
        int rq = 0;                                                             \
        if (EDGE_ON) {                                                          \
            int q = nt * 16 + c, qr = q >> 3, qc = q & 7;                       \
            rq = (e_wi ? (qr >= 4 ? 2 : 1) : 0) * 3 + (e_wj ? (qc >= 4 ? 2 : 1) : 0); \
        }                                                                       \
        float sv[16];                                                           \
        float sum = 0.f;                                                        \
        _Pragma("unroll")                                                       \
        for (int kt = 0; kt < 4; ++kt)                                          \
            _Pragma("unroll")                                                   \
            for (int i = 0; i < 4; ++i) {                                       \
                float s = stc[kt][i];                                           \
                if (EDGE_ON && (rk[kt][i] != rq)) s = -1e9f;                    \
                s = fast_exp2(s);                                               \
                sv[kt * 4 + i] = s;                                             \
                sum += s;                                                       \
            }                                                                   \
        sum += __shfl_xor(sum, 16);                                             \
        sum += __shfl_xor(sum, 32);                                             \
        const float rinv = fast_rcp(sum);                                       \
        f32x4 oa = zf;                                                          \
        _Pragma("unroll")                                                       \
        for (int ks2 = 0; ks2 < 4; ++ks2) {                                     \
            Upk pb;                                                             \
            pb.u[0] = pack2(sv[ks2 * 4 + 0], sv[ks2 * 4 + 1]);                  \
            pb.u[1] = pack2(sv[ks2 * 4 + 2], sv[ks2 * 4 + 3]);                  \
            oa = mfma16(avb[ks2], pb.s, oa);                                    \
        }                                                                       \
        uint2 hv;                                                               \
        hv.x = pack2(oa[0] * rinv, oa[1] * rinv);                               \
        hv.y = pack2(oa[2] * rinv, oa[3] * rinv);                               \
        *(uint2*)&o_hi[swz(nt * 16 + c, w * 16 + 4 * g)] = hv;                  \
    }

// 768 threads = 12 waves: waves 0-5 -> window wj0, waves 6-11 -> window wj0+1.
// r18 champion body, run TWICE per block (trip-2 fully-unrolled task loop):
// grid halves, fixed per-block latency amortizes, iter-2 staging is L2-hot.
__global__ __launch_bounds__(768, 4)
void swin_mfma(const float* __restrict__ x,
               const float* __restrict__ b_qkv,
               const float* __restrict__ b_out,
               const char*  __restrict__ ws,
               float* __restrict__ out)
{
    __shared__ char smem[32768];

    const int tid  = threadIdx.x;
    const int w2   = tid >> 6;          // wave 0..11
    const int wv   = (w2 >= 6) ? 1 : 0; // window half
    const int w    = w2 - 6 * wv;       // head 0..5
    const int lane = tid & 63;
    const int g    = lane >> 4;
    const int c    = lane & 15;
    const int tl   = tid - (wv << 8) - (wv << 7);   // tid - wv*384

    bf16_t* xs_hi = (bf16_t*)(smem + (wv << 14));   // phase 0/1 arena (swizzled [64][128])
    bf16_t* o_hi  = xs_hi;                          // phase 2/3 overlay

    const bf16_t* wqt   = (const bf16_t*)(ws + OFF_WQT);
    const bf16_t* wvp   = (const bf16_t*)(ws + OFF_WV);
    const bf16_t* wop   = (const bf16_t*)(ws + OFF_WO);
    const float*  rpe_b = (const float*)(ws + OFF_RPE);

    // loop-invariant hoisted weight frags
    const bf16x8 qh0 = *(const bf16x8*)&wqt[(w * 3 + 0) * 512 + lane * 8];
    const bf16x8 kh0 = *(const bf16x8*)&wqt[((6 + w) * 3 + 0) * 512 + lane * 8];
    const bf16x8 vh0 = *(const bf16x8*)&wvp[(w * 3 + 0) * 512 + lane * 8];

    const int r0  = tl / 24;            // staging decomposition (loop-invariant)
    const int c40 = tl - r0 * 24;

    const f32x4 zf = {0.f, 0.f, 0.f, 0.f};

    #pragma unroll
    for (int it2 = 0; it2 < 2; ++it2) {
        const int task = (blockIdx.x << 1) + it2;
        const int b   = task >> 9;                 // 512 tasks per image
        const int wi  = (task >> 4) & 31;
        const int wj  = ((task & 15) << 1) + wv;   // this half's window column

        if (it2) __syncthreads();   // guard: prev iter's phase-3 o_hi reads done

        // per-lane pixel indices for window rows p = t*16 + c (phase-3 stores)
        uint32_t pix[4];
        #pragma unroll
        for (int t = 0; t < 4; ++t) {
            int p = t * 16 + c;
            int gh = (wi * WSZ + (p >> 3) + 4) & 255;
            int gw = (wj * WSZ + (p & 7) + 4) & 255;
            pix[t] = (((uint32_t)b * HH + gh) << 8) + gw;
        }

        // ---- Phase 0: stage x (bf16) -> swizzled xs_hi (shifted gather) ----
        #pragma unroll
        for (int it = 0; it < 4; ++it) {
            int row = r0 + it * 16;
            int r = row >> 3, cl = row & 7;
            int gh = (wi * WSZ + r + 4) & 255;
            int gw = (wj * WSZ + cl + 4) & 255;
            const float4 v = *(const float4*)(x + (((size_t)b * HH + gh) * HH + gw) * DD + c40 * 4);
            uint2 hv;
            hv.x = pack2(v.x, v.y); hv.y = pack2(v.z, v.w);
            *(uint2*)&xs_hi[swz(row, c40 * 4)] = hv;
        }
        __syncthreads();   // barrier 1: staging complete

        // ---- Phase 1: QKV projection, plain bf16 ----
        __builtin_amdgcn_s_setprio(1);
        f32x4 aq[4], akk[4], av[4];
        {
            const float4 bq4 = *(const float4*)&b_qkv[w * 16 + 4 * g];
            const float4 bk4 = *(const float4*)&b_qkv[96 + w * 16 + 4 * g];
            const float  bv  = b_qkv[192 + w * 16 + c];
            #pragma unroll
            for (int t4 = 0; t4 < 4; ++t4) {
                aq[t4]  = (f32x4){bq4.x, bq4.y, bq4.z, bq4.w};
                akk[t4] = (f32x4){bk4.x, bk4.y, bk4.z, bk4.w};
                av[t4]  = (f32x4){bv, bv, bv, bv};
            }
        }
        #pragma unroll
        for (int ks = 0; ks < 3; ++ks) {
            bf16x8 ah[4];
            #pragma unroll
            for (int mt = 0; mt < 4; ++mt) {
                int e = (mt * 16 + c) * 128 + (((ks * 4 + g) ^ c) << 3);
                ah[mt] = *(const bf16x8*)&xs_hi[e];
            }
            const bf16x8 qh = (ks == 0) ? qh0 : *(const bf16x8*)&wqt[(w * 3 + ks) * 512 + lane * 8];
            const bf16x8 kh = (ks == 0) ? kh0 : *(const bf16x8*)&wqt[((6 + w) * 3 + ks) * 512 + lane * 8];
            const bf16x8 vh = (ks == 0) ? vh0 : *(const bf16x8*)&wvp[(w * 3 + ks) * 512 + lane * 8];
            #pragma unroll
            for (int mt = 0; mt < 4; ++mt) {
                aq[mt]  = __builtin_amdgcn_mfma_f32_16x16x32_bf16(qh, ah[mt], aq[mt], 0, 0, 0);
                akk[mt] = __builtin_amdgcn_mfma_f32_16x16x32_bf16(kh, ah[mt], akk[mt], 0, 0, 0);
                av[mt]  = __builtin_amdgcn_mfma_f32_16x16x32_bf16(ah[mt], vh, av[mt], 0, 0, 0);
            }
        }
        __syncthreads();   // barrier 2: all proj reads of xs done -> o overlay legal

        // convert proj outputs to 16x16x16 MFMA fragments (all lane-local)
        s16x4 aqb[4], akb[4], avb[4];
        #pragma unroll
        for (int t = 0; t < 4; ++t) {
            Upk uq, uk, uv;
            const float qs = 0.25f * LOG2E;     // fold 1/sqrt(dk) and log2e
            uq.u[0] = pack2(aq[t][0] * qs, aq[t][1] * qs);
            uq.u[1] = pack2(aq[t][2] * qs, aq[t][3] * qs);
            uk.u[0] = pack2(akk[t][0], akk[t][1]);
            uk.u[1] = pack2(akk[t][2], akk[t][3]);
            uv.u[0] = pack2(av[t][0], av[t][1]);
            uv.u[1] = pack2(av[t][2], av[t][3]);
            aqb[t] = uq.s; akb[t] = uk.s; avb[t] = uv.s;
        }

        // ---- Phase 2: attention, fully in registers; wave-uniform edge branch ----
        const int e_wi = (wi == 31), e_wj = (wj == 31);
        const bool edge = e_wi || e_wj;
        int rk[4][4];
        if (edge) {
            #pragma unroll
            for (int kt = 0; kt < 4; ++kt)
                #pragma unroll
                for (int i = 0; i < 4; ++i) {
                    int k = kt * 16 + g * 4 + i;
                    int kr = k >> 3, kc = k & 7;
                    rk[kt][i] = (e_wi ? (kr >= 4 ? 2 : 1) : 0) * 3 + (e_wj ? (kc >= 4 ? 2 : 1) : 0);
                }
            ATTN_LOOP(1)
        } else {
            ATTN_LOOP(0)
        }
        __syncthreads();   // barrier 3: o complete -> phase 3 reads

        // ---- Phase 3: out-projection, TRANSPOSED (A = Wo frags, B = o frags) ----
        f32x4 acc3[4];
        {
            const float4 bo4 = *(const float4*)&b_out[w * 16 + 4 * g];
            #pragma unroll
            for (int nt = 0; nt < 4; ++nt)
                acc3[nt] = (f32x4){bo4.x, bo4.y, bo4.z, bo4.w};
        }
        #pragma unroll
        for (int ks = 0; ks < 3; ++ks) {
            bf16x8 oh[4];
            #pragma unroll
            for (int nt = 0; nt < 4; ++nt) {
                int e = (nt * 16 + c) * 128 + (((ks * 4 + g) ^ c) << 3);
                oh[nt] = *(const bf16x8*)&o_hi[e];
            }
            const bf16x8 bh = *(const bf16x8*)&wop[(w * 3 + ks) * 512 + lane * 8];
            #pragma unroll
            for (int nt = 0; nt < 4; ++nt)
                acc3[nt] = __builtin_amdgcn_mfma_f32_16x16x32_bf16(bh, oh[nt], acc3[nt], 0, 0, 0);
        }
        __builtin_amdgcn_s_setprio(0);
        // store (shifted scatter): lane(c,g) holds out[pixel(nt*16+c)][w*16+4g..+3]
        #pragma unroll
        for (int nt = 0; nt < 4; ++nt)
            *(f32x4*)(out + (size_t)pix[nt] * DD + w * 16 + 4 * g) = acc3[nt];
    }
}

extern "C" void kernel_launch(void* const* d_in, const int* in_sizes, int n_in,
                              void* d_out, int out_size, void* d_ws, size_t ws_size,
                              hipStream_t stream) {
    const float* x    = (const float*)d_in[0];
    const float* wqkv = (const float*)d_in[1];
    const float* bqkv = (const float*)d_in[2];
    const float* wout = (const float*)d_in[3];
    const float* bout = (const float*)d_in[4];
    const float* rpe  = (const float*)d_in[5];
    float* out = (float*)d_out;
    char* ws = (char*)d_ws;

    const int B = in_sizes[0] / (HH * HH * DD);

    hipLaunchKernelGGL(prep_kernel, dim3(96), dim3(256), 0, stream, wqkv, wout, rpe, ws);
    hipLaunchKernelGGL(swin_mfma, dim3(B * 256), dim3(768), 0, stream,
                       x, bqkv, bout, (const char*)ws, out);
}

// Round 20
// 156.200 us; speedup vs baseline: 1.1610x; 1.1610x over previous
//
#include <hip/hip_runtime.h>
#include <stdint.h>

#define HH    256
#define DD    96
#define NH    6
#define WSZ   8

typedef __bf16 bf16_t;
typedef bf16_t bf16x8 __attribute__((ext_vector_type(8)));
typedef short  s16x4  __attribute__((ext_vector_type(4)));
typedef float  f32x4  __attribute__((ext_vector_type(4)));

union U2  { bf16_t h[2]; uint32_t u; };
union Upk { uint32_t u[2]; s16x4 s; };

#define LOG2E 1.44269504088896f

static __device__ __forceinline__ uint32_t pack2(float a, float b) {
    U2 x; x.h[0] = (bf16_t)a; x.h[1] = (bf16_t)b; return x.u;
}

static __device__ __forceinline__ f32x4 mfma16(s16x4 a, s16x4 b, f32x4 c) {
#if __has_builtin(__builtin_amdgcn_mfma_f32_16x16x16bf16_1k)
    return __builtin_amdgcn_mfma_f32_16x16x16bf16_1k(a, b, c, 0, 0, 0);
#else
    f32x4 d;
    asm volatile("v_mfma_f32_16x16x16_bf16 %0, %1, %2, %3"
                 : "=v"(d) : "v"(a), "v"(b), "v"(c));
    return d;
#endif
}

static __device__ __forceinline__ float fast_exp2(float x) {
#if __has_builtin(__builtin_amdgcn_exp2f)
    return __builtin_amdgcn_exp2f(x);
#else
    return exp2f(x);
#endif
}

static __device__ __forceinline__ float fast_rcp(float x) {
#if __has_builtin(__builtin_amdgcn_rcpf)
    return __builtin_amdgcn_rcpf(x);
#else
    return 1.0f / x;
#endif
}

// ---- workspace layout (bytes) ----
#define OFF_WQT  0        // Q,K transposed A-frags (bf16): 36 frags * 512 el = 36864 B
#define OFF_WV   36864    // V B-frags: 18 frags * 512 el = 18432 B
#define OFF_WO   55296    // out-proj frags: 18 frags = 18432 B
#define OFF_RPE  73728    // rpe * log2e in C-frag layout [h][nt][kt][lane][4] f32 = 98304 B
// total 172032 B

// swizzled element index into a [64][128] bf16 buffer (16B-chunk XOR)
static __device__ __forceinline__ int swz(int row, int col) {
    return row * 128 + ((((col >> 3) ^ (row & 15)) & 15) << 3) + (col & 7);
}

__global__ __launch_bounds__(256)
void prep_kernel(const float* __restrict__ wqkv, const float* __restrict__ wout,
                 const float* __restrict__ rpe, char* __restrict__ ws)
{
    bf16_t* wqt = (bf16_t*)(ws + OFF_WQT);
    bf16_t* wv  = (bf16_t*)(ws + OFF_WV);
    bf16_t* wo  = (bf16_t*)(ws + OFF_WO);
    float*  rpe_b = (float*)(ws + OFF_RPE);

    int idx = blockIdx.x * 256 + threadIdx.x;
    {
        int j = idx & 7, lane = (idx >> 3) & 63, frag = idx >> 9;
        int c = lane & 15, g = lane >> 4;
        // Q,K transposed A-frags: lane(c,g) holds W^T[head-dim c][k=ks*32+g*8+j]
        if (idx < 18432) {
            int ks = frag % 3, r2 = frag / 3, wh = r2 % 6, t = r2 / 6;  // t: 0=Q,1=K
            int k = ks * 32 + g * 8 + j;
            wqt[idx] = (bf16_t)wqkv[k * 288 + t * 96 + wh * 16 + c];
        }
        // V B-frags + out-proj frags: lane(c,g) holds W[k=ks*32+g*8+j][n=wh*16+c]
        if (idx < 9216) {
            int ks = frag % 3, wh = frag / 3;
            int k = ks * 32 + g * 8 + j;
            wv[idx] = (bf16_t)wqkv[k * 288 + 192 + wh * 16 + c];
            wo[idx] = (bf16_t)wout[k * 96 + wh * 16 + c];
        }
    }
    // rpe * log2e in QK^T C-fragment layout: [h][nt][kt][lane][i]
    if (idx < 24576) {
        int i = idx & 3, lane = (idx >> 2) & 63, kt = (idx >> 8) & 3,
            nt = (idx >> 10) & 3, h = idx >> 12;
        int c = lane & 15, g = lane >> 4;
        int k = kt * 16 + g * 4 + i, q = nt * 16 + c;
        int qr = q >> 3, qc = q & 7, kr = k >> 3, kc = k & 7;
        rpe_b[idx] = rpe[((qr - kr + 7) * 15 + (qc - kc + 7)) * NH + h] * LOG2E;
    }
}

// one nt-tile of the attention phase; EDGE_ON is a compile-time 0/1
#define ATTN_LOOP(EDGE_ON)                                                      \
    _Pragma("unroll")                                                           \
    for (int nt = 0; nt < 4; ++nt) {                                            \
        f32x4 stc[4];                                                           \
        _Pragma("unroll")                                                       \
        for (int kt = 0; kt < 4; ++kt) {                                        \
            const f32x4 rc = *(const f32x4*)&rpe_b[(((w * 4 + nt) * 4 + kt) << 8) + lane * 4]; \
            stc[kt] = mfma16(akb[kt], aqb[nt], rc);                             \
        }                                                                       \
        int rq = 0;                                                             \
        if (EDGE_ON) {                                                          \
            int q = nt * 16 + c, qr = q >> 3, qc = q & 7;                       \
            rq = (e_wi ? (qr >= 4 ? 2 : 1) : 0) * 3 + (e_wj ? (qc >= 4 ? 2 : 1) : 0); \
        }                                                                       \
        float sv[16];                                                           \
        float sum = 0.f;                                                        \
        _Pragma("unroll")                                                       \
        for (int kt = 0; kt < 4; ++kt)                                          \
            _Pragma("unroll")                                                   \
            for (int i = 0; i < 4; ++i) {                                       \
                float s = stc[kt][i];                                           \
                if (EDGE_ON && (rk[kt][i] != rq)) s = -1e9f;                    \
                s = fast_exp2(s);                                               \
                sv[kt * 4 + i] = s;                                             \
                sum += s;                                                       \
            }                                                                   \
        sum += __shfl_xor(sum, 16);                                             \
        sum += __shfl_xor(sum, 32);                                             \
        const float rinv = fast_rcp(sum);                                       \
        f32x4 oa = zf;                                                          \
        _Pragma("unroll")                                                       \
        for (int ks2 = 0; ks2 < 4; ++ks2) {                                     \
            Upk pb;                                                             \
            pb.u[0] = pack2(sv[ks2 * 4 + 0], sv[ks2 * 4 + 1]);                  \
            pb.u[1] = pack2(sv[ks2 * 4 + 2], sv[ks2 * 4 + 3]);                  \
            oa = mfma16(avb[ks2], pb.s, oa);                                    \
        }                                                                       \
        uint2 hv;                                                               \
        hv.x = pack2(oa[0] * rinv, oa[1] * rinv);                               \
        hv.y = pack2(oa[2] * rinv, oa[3] * rinv);                               \
        *(uint2*)&o_hi[swz(nt * 16 + c, w * 16 + 4 * g)] = hv;                  \
    }

// 768 threads = 12 waves: waves 0-5 -> window wj0, waves 6-11 -> window wj0+1.
// r16/r18 champion structure: 32 KB static LDS, xs/o overlay per half, 3 barriers,
// all-bf16 weights, transposed phase-3, setprio(1) spanning phases 1-3.
__global__ __launch_bounds__(768, 4)
void swin_mfma(const float* __restrict__ x,
               const float* __restrict__ b_qkv,
               const float* __restrict__ b_out,
               const char*  __restrict__ ws,
               float* __restrict__ out)
{
    __shared__ char smem[32768];

    const int tid  = threadIdx.x;
    const int w2   = tid >> 6;          // wave 0..11
    const int wv   = (w2 >= 6) ? 1 : 0; // window half
    const int w    = w2 - 6 * wv;       // head 0..5
    const int lane = tid & 63;
    const int g    = lane >> 4;
    const int c    = lane & 15;
    const int tl   = tid - (wv << 8) - (wv << 7);   // tid - wv*384

    bf16_t* xs_hi = (bf16_t*)(smem + (wv << 14));   // phase 0/1 arena (swizzled [64][128])
    bf16_t* o_hi  = xs_hi;                          // phase 2/3 overlay

    const bf16_t* wqt   = (const bf16_t*)(ws + OFF_WQT);
    const bf16_t* wvp   = (const bf16_t*)(ws + OFF_WV);
    const bf16_t* wop   = (const bf16_t*)(ws + OFF_WO);
    const float*  rpe_b = (const float*)(ws + OFF_RPE);

    const int blk = blockIdx.x;
    const int b   = blk >> 9;                 // 512 blocks per image
    const int wi  = (blk >> 4) & 31;
    const int wj  = ((blk & 15) << 1) + wv;   // this half's window column

    // hoisted ks=0 weight frags: VMEM issued before the staging barrier,
    // latency drains during the barrier's vmcnt(0) wait.
    const bf16x8 qh0 = *(const bf16x8*)&wqt[(w * 3 + 0) * 512 + lane * 8];
    const bf16x8 kh0 = *(const bf16x8*)&wqt[((6 + w) * 3 + 0) * 512 + lane * 8];
    const bf16x8 vh0 = *(const bf16x8*)&wvp[(w * 3 + 0) * 512 + lane * 8];

    // per-lane pixel indices for window rows p = t*16 + c (phase-3 stores)
    uint32_t pix[4];
    #pragma unroll
    for (int t = 0; t < 4; ++t) {
        int p = t * 16 + c;
        int gh = (wi * WSZ + (p >> 3) + 4) & 255;
        int gw = (wj * WSZ + (p & 7) + 4) & 255;
        pix[t] = (((uint32_t)b * HH + gh) << 8) + gw;
    }

    const f32x4 zf = {0.f, 0.f, 0.f, 0.f};

    // ---- Phase 0: stage x (bf16) -> swizzled xs_hi (shifted gather) ----
    {
        const int r0  = tl / 24;          // hoisted: 384/24 = 16 rows per it-step
        const int c40 = tl - r0 * 24;
        #pragma unroll
        for (int it = 0; it < 4; ++it) {
            int row = r0 + it * 16;
            int r = row >> 3, cl = row & 7;
            int gh = (wi * WSZ + r + 4) & 255;
            int gw = (wj * WSZ + cl + 4) & 255;
            const float4 v = *(const float4*)(x + (((size_t)b * HH + gh) * HH + gw) * DD + c40 * 4);
            uint2 hv;
            hv.x = pack2(v.x, v.y); hv.y = pack2(v.z, v.w);
            *(uint2*)&xs_hi[swz(row, c40 * 4)] = hv;
        }
    }
    __syncthreads();   // barrier 1: staging complete (drains hoisted weight loads too)

    // ---- Phase 1: QKV projection, plain bf16 ----
    __builtin_amdgcn_s_setprio(1);
    f32x4 aq[4], akk[4], av[4];
    {
        const float4 bq4 = *(const float4*)&b_qkv[w * 16 + 4 * g];
        const float4 bk4 = *(const float4*)&b_qkv[96 + w * 16 + 4 * g];
        const float  bv  = b_qkv[192 + w * 16 + c];
        #pragma unroll
        for (int t4 = 0; t4 < 4; ++t4) {
            aq[t4]  = (f32x4){bq4.x, bq4.y, bq4.z, bq4.w};
            akk[t4] = (f32x4){bk4.x, bk4.y, bk4.z, bk4.w};
            av[t4]  = (f32x4){bv, bv, bv, bv};
        }
    }
    #pragma unroll
    for (int ks = 0; ks < 3; ++ks) {
        bf16x8 ah[4];
        #pragma unroll
        for (int mt = 0; mt < 4; ++mt) {
            int e = (mt * 16 + c) * 128 + (((ks * 4 + g) ^ c) << 3);
            ah[mt] = *(const bf16x8*)&xs_hi[e];
        }
        const bf16x8 qh = (ks == 0) ? qh0 : *(const bf16x8*)&wqt[(w * 3 + ks) * 512 + lane * 8];
        const bf16x8 kh = (ks == 0) ? kh0 : *(const bf16x8*)&wqt[((6 + w) * 3 + ks) * 512 + lane * 8];
        const bf16x8 vh = (ks == 0) ? vh0 : *(const bf16x8*)&wvp[(w * 3 + ks) * 512 + lane * 8];
        #pragma unroll
        for (int mt = 0; mt < 4; ++mt) {
            aq[mt]  = __builtin_amdgcn_mfma_f32_16x16x32_bf16(qh, ah[mt], aq[mt], 0, 0, 0);
            akk[mt] = __builtin_amdgcn_mfma_f32_16x16x32_bf16(kh, ah[mt], akk[mt], 0, 0, 0);
            av[mt]  = __builtin_amdgcn_mfma_f32_16x16x32_bf16(ah[mt], vh, av[mt], 0, 0, 0);
        }
    }
    __syncthreads();   // barrier 2: all proj reads of xs done -> o overlay legal

    // convert proj outputs to 16x16x16 MFMA fragments (all lane-local)
    s16x4 aqb[4], akb[4], avb[4];
    #pragma unroll
    for (int t = 0; t < 4; ++t) {
        Upk uq, uk, uv;
        const float qs = 0.25f * LOG2E;     // fold 1/sqrt(dk) and log2e
        uq.u[0] = pack2(aq[t][0] * qs, aq[t][1] * qs);
        uq.u[1] = pack2(aq[t][2] * qs, aq[t][3] * qs);
        uk.u[0] = pack2(akk[t][0], akk[t][1]);
        uk.u[1] = pack2(akk[t][2], akk[t][3]);
        uv.u[0] = pack2(av[t][0], av[t][1]);
        uv.u[1] = pack2(av[t][2], av[t][3]);
        aqb[t] = uq.s; akb[t] = uk.s; avb[t] = uv.s;
    }

    // ---- Phase 2: attention, fully in registers; wave-uniform edge branch ----
    const int e_wi = (wi == 31), e_wj = (wj == 31);
    const bool edge = e_wi || e_wj;
    int rk[4][4];
    if (edge) {
        #pragma unroll
        for (int kt = 0; kt < 4; ++kt)
            #pragma unroll
            for (int i = 0; i < 4; ++i) {
                int k = kt * 16 + g * 4 + i;
                int kr = k >> 3, kc = k & 7;
                rk[kt][i] = (e_wi ? (kr >= 4 ? 2 : 1) : 0) * 3 + (e_wj ? (kc >= 4 ? 2 : 1) : 0);
            }
        ATTN_LOOP(1)
    } else {
        ATTN_LOOP(0)
    }
    __syncthreads();   // barrier 3: o complete -> phase 3 reads

    // ---- Phase 3: out-projection, TRANSPOSED (A = Wo frags, B = o frags) ----
    // C^T[outfeat = w*16+4g+i][pos = nt*16+c] -> per-lane dwordx4 stores
    f32x4 acc3[4];
    {
        const float4 bo4 = *(const float4*)&b_out[w * 16 + 4 * g];
        #pragma unroll
        for (int nt = 0; nt < 4; ++nt)
            acc3[nt] = (f32x4){bo4.x, bo4.y, bo4.z, bo4.w};
    }
    #pragma unroll
    for (int ks = 0; ks < 3; ++ks) {
        bf16x8 oh[4];
        #pragma unroll
        for (int nt = 0; nt < 4; ++nt) {
            int e = (nt * 16 + c) * 128 + (((ks * 4 + g) ^ c) << 3);
            oh[nt] = *(const bf16x8*)&o_hi[e];
        }
        const bf16x8 bh = *(const bf16x8*)&wop[(w * 3 + ks) * 512 + lane * 8];
        #pragma unroll
        for (int nt = 0; nt < 4; ++nt)
            acc3[nt] = __builtin_amdgcn_mfma_f32_16x16x32_bf16(bh, oh[nt], acc3[nt], 0, 0, 0);
    }
    __builtin_amdgcn_s_setprio(0);
    // store (shifted scatter): lane(c,g) holds out[pixel(nt*16+c)][w*16+4g..+3]
    #pragma unroll
    for (int nt = 0; nt < 4; ++nt)
        *(f32x4*)(out + (size_t)pix[nt] * DD + w * 16 + 4 * g) = acc3[nt];
}

extern "C" void kernel_launch(void* const* d_in, const int* in_sizes, int n_in,
                              void* d_out, int out_size, void* d_ws, size_t ws_size,
                              hipStream_t stream) {
    const float* x    = (const float*)d_in[0];
    const float* wqkv = (const float*)d_in[1];
    const float* bqkv = (const float*)d_in[2];
    const float* wout = (const float*)d_in[3];
    const float* bout = (const float*)d_in[4];
    const float* rpe  = (const float*)d_in[5];
    float* out = (float*)d_out;
    char* ws = (char*)d_ws;

    const int B = in_sizes[0] / (HH * HH * DD);

    hipLaunchKernelGGL(prep_kernel, dim3(96), dim3(256), 0, stream, wqkv, wout, rpe, ws);
    hipLaunchKernelGGL(swin_mfma, dim3(B * 512), dim3(768), 0, stream,
                       x, bqkv, bout, (const char*)ws, out);
}